// Round 7
// baseline (439.875 us; speedup 1.0000x reference)
//
#include <hip/hip_runtime.h>
#include <hip/hip_bf16.h>
#include <math.h>

// Problem constants (match reference)
#define NNODES 100000
#define NPAD   100032        // padded to multiple of 64 for guard-free GEMM
#define IN_DIM 128
#define HID 128
#define HEADS 2
#define F2 256               // HEADS*HID
#define NEDGES 800000
#define ETOT 900000          // NEDGES + NNODES self-loops
#define NEG_SLOPE 0.2f

typedef unsigned int uint;
typedef unsigned short ushort;
typedef __attribute__((ext_vector_type(8))) short short8;
typedef __attribute__((ext_vector_type(4))) float floatx4;

__device__ __forceinline__ ushort f2bf(float f) {
    uint u = __builtin_bit_cast(uint, f);
    u += 0x7fffu + ((u >> 16) & 1u);       // round-to-nearest-even
    return (ushort)(u >> 16);
}
__device__ __forceinline__ float bf2f(uint u16) {
    return __builtin_bit_cast(float, u16 << 16);
}
__device__ __forceinline__ float wred_sum(float v) {
    for (int o = 32; o; o >>= 1) v += __shfl_xor(v, o);
    return v;
}

// ---------------------------------------------------------------------------
// CSR build: histogram -> per-block scan -> fixup(+block-sum scan) -> scatter
// ---------------------------------------------------------------------------
__global__ __launch_bounds__(256) void hist_kernel(const int* __restrict__ ei,
                                                   int* __restrict__ deg) {
    int i = blockIdx.x * 256 + threadIdx.x;
    if (i >= ETOT) return;
    int dst = (i < NEDGES) ? ei[NEDGES + i] : (i - NEDGES);
    atomicAdd(&deg[dst], 1);
}

__global__ __launch_bounds__(256) void scan1_kernel(const int* __restrict__ deg,
                                                    int* __restrict__ row_start,
                                                    int* __restrict__ bsum) {
    __shared__ int s[256];
    int t = threadIdx.x;
    int i = blockIdx.x * 256 + t;
    int v = (i < NNODES) ? deg[i] : 0;
    s[t] = v;
    __syncthreads();
    for (int off = 1; off < 256; off <<= 1) {
        int x = (t >= off) ? s[t - off] : 0;
        __syncthreads();
        s[t] += x;
        __syncthreads();
    }
    if (i < NNODES) row_start[i] = s[t] - v;   // exclusive within block
    if (t == 255) bsum[blockIdx.x] = s[255];
}

// adds prefix of bsum (computed in-kernel) + writes cursor
__global__ __launch_bounds__(256) void scan_fix_kernel(int* __restrict__ row_start,
                                                       const int* __restrict__ bsum,
                                                       int* __restrict__ cursor) {
    __shared__ int sh[256];
    int t = threadIdx.x, bid = blockIdx.x;
    int v = 0;
    for (int k = t; k < bid; k += 256) v += bsum[k];
    sh[t] = v;
    __syncthreads();
    for (int off = 128; off; off >>= 1) {
        if (t < off) sh[t] += sh[t + off];
        __syncthreads();
    }
    int boff = sh[0];
    int i = bid * 256 + t;
    if (i == 0) row_start[NNODES] = ETOT;
    if (i < NNODES) {
        int r = row_start[i] + boff;
        row_start[i] = r;
        cursor[i] = r;
    }
}

__global__ __launch_bounds__(256) void scatter_kernel(const int* __restrict__ ei,
                                                      int* __restrict__ cursor,
                                                      int* __restrict__ csr_src) {
    int i = blockIdx.x * 256 + threadIdx.x;
    if (i >= ETOT) return;
    int src, dst;
    if (i < NEDGES) { src = ei[i]; dst = ei[NEDGES + i]; }
    else            { src = i - NEDGES; dst = src; }
    int pos = atomicAdd(&cursor[dst], 1);
    csr_src[pos] = src;
}

// ---------------------------------------------------------------------------
// merged prep: W1^T, W2^T (bf16), fused post_mp weights, deg zeroing
// grid = 776 blocks: [0,128) W1t, [128,384) W2t, 384 fw, [385,776) deg=0
// ---------------------------------------------------------------------------
__global__ __launch_bounds__(256) void prep_kernel(const float* __restrict__ W1,
                                                   ushort* __restrict__ W1t,
                                                   const float* __restrict__ W2,
                                                   ushort* __restrict__ W2t,
                                                   const float* __restrict__ Wp1,
                                                   const float* __restrict__ bp1,
                                                   const float* __restrict__ Wp2,
                                                   const float* __restrict__ bp2,
                                                   float2* __restrict__ Wf,
                                                   float* __restrict__ bfv,
                                                   int* __restrict__ deg) {
    int b = blockIdx.x, t = threadIdx.x;
    if (b < 128) {                       // W1t[n][k] = W1[k][n], K=128, N=256
        int i = b * 256 + t;
        int n = i >> 7, k = i & 127;
        W1t[n * 128 + k] = f2bf(W1[k * 256 + n]);
    } else if (b < 384) {                // W2t[n][k] = W2[k][n], K=256, N=256
        int i = (b - 128) * 256 + t;
        int n = i >> 8, k = i & 255;
        W2t[n * 256 + k] = f2bf(W2[k * 256 + n]);
    } else if (b == 384) {               // Wf[k] = Wp1[k][:] @ Wp2 ; bfv
        float s0 = 0.f, s1 = 0.f;
        for (int m = 0; m < 128; m++) {
            float w = Wp1[t * 128 + m];
            s0 += w * Wp2[2 * m];
            s1 += w * Wp2[2 * m + 1];
        }
        Wf[t] = make_float2(s0, s1);
        if (t < 2) {
            float bb = bp2[t];
            for (int m = 0; m < 128; m++) bb += bp1[m] * Wp2[2 * m + t];
            bfv[t] = bb;
        }
    } else {                             // zero deg
        int i = (b - 385) * 256 + t;
        if (i < NNODES) deg[i] = 0;
    }
}

// ---------------------------------------------------------------------------
// bf16 MFMA GEMM, block tile 64 rows x 128 cols (one full head per block y).
// 4 waves: wave w = rows w*16..w*16+15, all 128 cols (8 MFMA per BK=32).
// Fused alpha logits written NON-atomically (block covers the whole head).
// C-store via LDS transpose -> global_store_dwordx4.
// ---------------------------------------------------------------------------
__global__ __launch_bounds__(256) void mfma_gemm_f32A(const float* __restrict__ A,
                                                      const ushort* __restrict__ Bt,
                                                      ushort* __restrict__ C,
                                                      float* __restrict__ as_f,
                                                      float* __restrict__ ad_f,
                                                      const float* __restrict__ aS,
                                                      const float* __restrict__ aD,
                                                      int K) {
    __shared__ ushort As[64][40];
    __shared__ ushort Bs[128][40];
    int t = threadIdx.x;
    int wave = t >> 6, lane = t & 63;
    int quad = lane >> 4, l16 = lane & 15;
    size_t rowBase = (size_t)blockIdx.x * 64;
    int colBase = blockIdx.y * 128;
    int head = blockIdx.y;

    floatx4 acc[8];
#pragma unroll
    for (int i = 0; i < 8; i++) acc[i] = (floatx4){0.f, 0.f, 0.f, 0.f};

    int ar = t >> 2, ac = (t & 3) * 8;
    int agr = (int)rowBase + ar;
    const float*  Ap  = A + (size_t)agr * K + ac;
    const ushort* Bp0 = Bt + (size_t)(colBase + ar) * K + ac;
    const ushort* Bp1 = Bp0 + (size_t)64 * K;
    bool aok = agr < NNODES;

    for (int k0 = 0; k0 < K; k0 += 32) {
        float4 f0 = make_float4(0.f, 0.f, 0.f, 0.f), f1 = f0;
        if (aok) {
            f0 = *reinterpret_cast<const float4*>(Ap + k0);
            f1 = *reinterpret_cast<const float4*>(Ap + k0 + 4);
        }
        uint4 b0 = *reinterpret_cast<const uint4*>(Bp0 + k0);
        uint4 b1 = *reinterpret_cast<const uint4*>(Bp1 + k0);
        uint4 av;
        av.x = (uint)f2bf(f0.x) | ((uint)f2bf(f0.y) << 16);
        av.y = (uint)f2bf(f0.z) | ((uint)f2bf(f0.w) << 16);
        av.z = (uint)f2bf(f1.x) | ((uint)f2bf(f1.y) << 16);
        av.w = (uint)f2bf(f1.z) | ((uint)f2bf(f1.w) << 16);
        *reinterpret_cast<uint4*>(&As[ar][ac])      = av;
        *reinterpret_cast<uint4*>(&Bs[ar][ac])      = b0;
        *reinterpret_cast<uint4*>(&Bs[64 + ar][ac]) = b1;
        __syncthreads();

        union { uint4 u; short8 s; } afr, bfr;
        afr.u = *reinterpret_cast<const uint4*>(&As[wave * 16 + l16][quad * 8]);
#pragma unroll
        for (int nt = 0; nt < 8; nt++) {
            bfr.u = *reinterpret_cast<const uint4*>(&Bs[nt * 16 + l16][quad * 8]);
            acc[nt] = __builtin_amdgcn_mfma_f32_16x16x32_bf16(afr.s, bfr.s, acc[nt], 0, 0, 0);
        }
        __syncthreads();
    }

    // fused alpha logits over the full head (non-atomic), from registers
    {
        float aSv[8], aDv[8];
#pragma unroll
        for (int nt = 0; nt < 8; nt++) {
            int c = colBase + nt * 16 + l16;
            aSv[nt] = aS[c];
            aDv[nt] = aD[c];
        }
#pragma unroll
        for (int r = 0; r < 4; r++) {
            float ps = 0.f, pd = 0.f;
#pragma unroll
            for (int nt = 0; nt < 8; nt++) {
                ps += acc[nt][r] * aSv[nt];
                pd += acc[nt][r] * aDv[nt];
            }
#pragma unroll
            for (int o = 1; o < 16; o <<= 1) {
                ps += __shfl_xor(ps, o);
                pd += __shfl_xor(pd, o);
            }
            if (l16 == 0) {
                size_t row = rowBase + wave * 16 + quad * 4 + r;
                as_f[2 * row + head] = ps;
                ad_f[2 * row + head] = pd;
            }
        }
    }

    // C store via LDS transpose (two 64-col halves), uint4 global stores
    ushort* lbuf = &Bs[0][0];            // reuse B staging (>= 64*72 ushorts)
#pragma unroll
    for (int half = 0; half < 2; half++) {
        __syncthreads();
#pragma unroll
        for (int nt4 = 0; nt4 < 4; nt4++) {
            int nt = half * 4 + nt4;
            int col = nt4 * 16 + l16;
#pragma unroll
            for (int r = 0; r < 4; r++) {
                int row = wave * 16 + quad * 4 + r;
                lbuf[row * 72 + col] = f2bf(acc[nt][r]);
            }
        }
        __syncthreads();
        int row = t >> 2;
        int ch = t & 3;
        uint4 v0 = *reinterpret_cast<const uint4*>(&lbuf[row * 72 + ch * 8]);
        uint4 v1 = *reinterpret_cast<const uint4*>(&lbuf[row * 72 + 32 + ch * 8]);
        size_t g = (rowBase + row) * (size_t)F2 + colBase + half * 64;
        *reinterpret_cast<uint4*>(&C[g + ch * 8]) = v0;
        *reinterpret_cast<uint4*>(&C[g + 32 + ch * 8]) = v1;
    }
}

// same but A already bf16 (padded, no guard)
__global__ __launch_bounds__(256) void mfma_gemm_bf16A(const ushort* __restrict__ A,
                                                       const ushort* __restrict__ Bt,
                                                       ushort* __restrict__ C,
                                                       float* __restrict__ as_f,
                                                       float* __restrict__ ad_f,
                                                       const float* __restrict__ aS,
                                                       const float* __restrict__ aD,
                                                       int K) {
    __shared__ ushort As[64][40];
    __shared__ ushort Bs[128][40];
    int t = threadIdx.x;
    int wave = t >> 6, lane = t & 63;
    int quad = lane >> 4, l16 = lane & 15;
    size_t rowBase = (size_t)blockIdx.x * 64;
    int colBase = blockIdx.y * 128;
    int head = blockIdx.y;

    floatx4 acc[8];
#pragma unroll
    for (int i = 0; i < 8; i++) acc[i] = (floatx4){0.f, 0.f, 0.f, 0.f};

    int ar = t >> 2, ac = (t & 3) * 8;
    const ushort* Ap  = A + (rowBase + ar) * K + ac;
    const ushort* Bp0 = Bt + (size_t)(colBase + ar) * K + ac;
    const ushort* Bp1 = Bp0 + (size_t)64 * K;

    for (int k0 = 0; k0 < K; k0 += 32) {
        uint4 av = *reinterpret_cast<const uint4*>(Ap + k0);
        uint4 b0 = *reinterpret_cast<const uint4*>(Bp0 + k0);
        uint4 b1 = *reinterpret_cast<const uint4*>(Bp1 + k0);
        *reinterpret_cast<uint4*>(&As[ar][ac])      = av;
        *reinterpret_cast<uint4*>(&Bs[ar][ac])      = b0;
        *reinterpret_cast<uint4*>(&Bs[64 + ar][ac]) = b1;
        __syncthreads();

        union { uint4 u; short8 s; } afr, bfr;
        afr.u = *reinterpret_cast<const uint4*>(&As[wave * 16 + l16][quad * 8]);
#pragma unroll
        for (int nt = 0; nt < 8; nt++) {
            bfr.u = *reinterpret_cast<const uint4*>(&Bs[nt * 16 + l16][quad * 8]);
            acc[nt] = __builtin_amdgcn_mfma_f32_16x16x32_bf16(afr.s, bfr.s, acc[nt], 0, 0, 0);
        }
        __syncthreads();
    }

    {
        float aSv[8], aDv[8];
#pragma unroll
        for (int nt = 0; nt < 8; nt++) {
            int c = colBase + nt * 16 + l16;
            aSv[nt] = aS[c];
            aDv[nt] = aD[c];
        }
#pragma unroll
        for (int r = 0; r < 4; r++) {
            float ps = 0.f, pd = 0.f;
#pragma unroll
            for (int nt = 0; nt < 8; nt++) {
                ps += acc[nt][r] * aSv[nt];
                pd += acc[nt][r] * aDv[nt];
            }
#pragma unroll
            for (int o = 1; o < 16; o <<= 1) {
                ps += __shfl_xor(ps, o);
                pd += __shfl_xor(pd, o);
            }
            if (l16 == 0) {
                size_t row = rowBase + wave * 16 + quad * 4 + r;
                as_f[2 * row + head] = ps;
                ad_f[2 * row + head] = pd;
            }
        }
    }

    ushort* lbuf = &Bs[0][0];
#pragma unroll
    for (int half = 0; half < 2; half++) {
        __syncthreads();
#pragma unroll
        for (int nt4 = 0; nt4 < 4; nt4++) {
            int nt = half * 4 + nt4;
            int col = nt4 * 16 + l16;
#pragma unroll
            for (int r = 0; r < 4; r++) {
                int row = wave * 16 + quad * 4 + r;
                lbuf[row * 72 + col] = f2bf(acc[nt][r]);
            }
        }
        __syncthreads();
        int row = t >> 2;
        int ch = t & 3;
        uint4 v0 = *reinterpret_cast<const uint4*>(&lbuf[row * 72 + ch * 8]);
        uint4 v1 = *reinterpret_cast<const uint4*>(&lbuf[row * 72 + 32 + ch * 8]);
        size_t g = (rowBase + row) * (size_t)F2 + colBase + half * 64;
        *reinterpret_cast<uint4*>(&C[g + ch * 8]) = v0;
        *reinterpret_cast<uint4*>(&C[g + 32 + ch * 8]) = v1;
    }
}

// ---------------------------------------------------------------------------
// fully-fused segment softmax + weighted gather. Wave per node, no LDS,
// no reductions (per-lane full selected-head weight sum = denominator).
// Round-4 structure: 4 independent 512B row loads in flight, serial tail.
// final_mode: 0 = write bf16 row (relu), 1 = fuse post_mp GEMV + sigmoid.
// ---------------------------------------------------------------------------
__device__ __forceinline__ float edge_w(float2 q, float adsel, bool head1) {
    float l = (head1 ? q.y : q.x) + adsel;
    l = l > 0.f ? l : NEG_SLOPE * l;
    return __expf(l);
}

__global__ __launch_bounds__(256) void gather_kernel(const uint2* __restrict__ hb2,
                                                     const int* __restrict__ row_start,
                                                     const int* __restrict__ csr_src,
                                                     const float2* __restrict__ as_,
                                                     const float2* __restrict__ ad_,
                                                     const float4* __restrict__ bias4,
                                                     uint2* __restrict__ outb2,
                                                     const float4* __restrict__ WfA,
                                                     const float* __restrict__ bfv,
                                                     float2* __restrict__ outp,
                                                     int final_mode) {
    int wave = threadIdx.x >> 6, lane = threadIdx.x & 63;
    int n = blockIdx.x * 4 + wave;
    if (n >= NNODES) return;
    int beg = row_start[n], end = row_start[n + 1];
    float2 ad = ad_[n];
    bool head1 = lane >= 32;   // lanes 0-31: head0 feats, 32-63: head1 feats
    float adsel = head1 ? ad.y : ad.x;

    float a0 = 0.f, a1 = 0.f, a2 = 0.f, a3 = 0.f;
    float aden = 0.f;

    int j = beg;
    for (; j + 3 < end; j += 4) {
        int s0 = csr_src[j],     s1 = csr_src[j + 1];
        int s2 = csr_src[j + 2], s3 = csr_src[j + 3];
        float2 q0 = as_[s0], q1 = as_[s1], q2 = as_[s2], q3 = as_[s3];
        uint2 h0 = hb2[(size_t)s0 * 64 + lane];
        uint2 h1 = hb2[(size_t)s1 * 64 + lane];
        uint2 h2 = hb2[(size_t)s2 * 64 + lane];
        uint2 h3 = hb2[(size_t)s3 * 64 + lane];
        float w0 = edge_w(q0, adsel, head1), w1 = edge_w(q1, adsel, head1);
        float w2 = edge_w(q2, adsel, head1), w3 = edge_w(q3, adsel, head1);
        aden += (w0 + w1) + (w2 + w3);
        a0 += w0 * bf2f(h0.x & 0xffffu) + w1 * bf2f(h1.x & 0xffffu)
            + w2 * bf2f(h2.x & 0xffffu) + w3 * bf2f(h3.x & 0xffffu);
        a1 += w0 * bf2f(h0.x >> 16) + w1 * bf2f(h1.x >> 16)
            + w2 * bf2f(h2.x >> 16) + w3 * bf2f(h3.x >> 16);
        a2 += w0 * bf2f(h0.y & 0xffffu) + w1 * bf2f(h1.y & 0xffffu)
            + w2 * bf2f(h2.y & 0xffffu) + w3 * bf2f(h3.y & 0xffffu);
        a3 += w0 * bf2f(h0.y >> 16) + w1 * bf2f(h1.y >> 16)
            + w2 * bf2f(h2.y >> 16) + w3 * bf2f(h3.y >> 16);
    }
    for (; j < end; j++) {
        int s = csr_src[j];
        float2 q = as_[s];
        uint2 hv = hb2[(size_t)s * 64 + lane];
        float w = edge_w(q, adsel, head1);
        aden += w;
        a0 += w * bf2f(hv.x & 0xffffu);
        a1 += w * bf2f(hv.x >> 16);
        a2 += w * bf2f(hv.y & 0xffffu);
        a3 += w * bf2f(hv.y >> 16);
    }

    float inv = 1.f / (aden + 1e-16f);
    float4 b = bias4[lane];
    float o0 = fmaxf(a0 * inv + b.x, 0.f);
    float o1 = fmaxf(a1 * inv + b.y, 0.f);
    float o2 = fmaxf(a2 * inv + b.z, 0.f);
    float o3 = fmaxf(a3 * inv + b.w, 0.f);
    if (!final_mode) {
        uint2 pk;
        pk.x = (uint)f2bf(o0) | ((uint)f2bf(o1) << 16);
        pk.y = (uint)f2bf(o2) | ((uint)f2bf(o3) << 16);
        outb2[(size_t)n * 64 + lane] = pk;
    } else {
        float4 wa = WfA[2 * lane];
        float4 wb = WfA[2 * lane + 1];
        float p0 = o0 * wa.x + o1 * wa.z + o2 * wb.x + o3 * wb.z;
        float p1 = o0 * wa.y + o1 * wa.w + o2 * wb.y + o3 * wb.w;
        p0 = wred_sum(p0);
        p1 = wred_sum(p1);
        if (lane == 0) {
            float2 r;
            r.x = 1.f / (1.f + __expf(-(p0 + bfv[0])));
            r.y = 1.f / (1.f + __expf(-(p1 + bfv[1])));
            outp[n] = r;
        }
    }
}

// ---------------------------------------------------------------------------
extern "C" void kernel_launch(void* const* d_in, const int* in_sizes, int n_in,
                              void* d_out, int out_size, void* d_ws, size_t ws_size,
                              hipStream_t stream) {
    const float* x      = (const float*)d_in[0];
    const int*   ei     = (const int*)d_in[1];
    const float* W1     = (const float*)d_in[2];
    const float* a_src1 = (const float*)d_in[3];
    const float* a_dst1 = (const float*)d_in[4];
    const float* b1     = (const float*)d_in[5];
    const float* W2     = (const float*)d_in[6];
    const float* a_src2 = (const float*)d_in[7];
    const float* a_dst2 = (const float*)d_in[8];
    const float* b2     = (const float*)d_in[9];
    const float* Wp1    = (const float*)d_in[10];
    const float* bp1    = (const float*)d_in[11];
    const float* Wp2    = (const float*)d_in[12];
    const float* bp2    = (const float*)d_in[13];
    float* outp = (float*)d_out;

    // workspace carve-up (all regions 16B aligned)
    char* w = (char*)d_ws;
    ushort* hbf  = (ushort*)w; w += (size_t)NPAD * 256 * sizeof(ushort);  // 51.2MB
    ushort* obf  = (ushort*)w; w += (size_t)NPAD * 256 * sizeof(ushort);  // 51.2MB
    ushort* W1t  = (ushort*)w; w += (size_t)256 * 128 * sizeof(ushort);
    ushort* W2t  = (ushort*)w; w += (size_t)256 * 256 * sizeof(ushort);
    float2* Wf   = (float2*)w; w += 256 * sizeof(float2);
    float*  bfv  = (float*)w;  w += 4 * sizeof(float);
    float2* as_  = (float2*)w; w += (size_t)NPAD * sizeof(float2);
    float2* ad_  = (float2*)w; w += (size_t)NPAD * sizeof(float2);
    int* deg       = (int*)w; w += (size_t)NNODES * sizeof(int);
    int* row_start = (int*)w; w += (size_t)(NNODES + 16) * sizeof(int);
    int* cursor    = (int*)w; w += (size_t)NNODES * sizeof(int);
    int* csr_src   = (int*)w; w += (size_t)ETOT * sizeof(int);
    int* bsum      = (int*)w; w += 512 * sizeof(int);

    const int SCAN_BLOCKS = (NNODES + 255) / 256;   // 391
    const int NODE_WAVES  = (NNODES + 3) / 4;       // 25000
    const int MB = NPAD / 64;                       // 1563

    // --- prep (weights + deg zeroing) ---
    prep_kernel<<<776, 256, 0, stream>>>(W1, W1t, W2, W2t, Wp1, bp1, Wp2, bp2,
                                         Wf, bfv, deg);

    // --- CSR build ---
    hist_kernel<<<(ETOT + 255) / 256, 256, 0, stream>>>(ei, deg);
    scan1_kernel<<<SCAN_BLOCKS, 256, 0, stream>>>(deg, row_start, bsum);
    scan_fix_kernel<<<SCAN_BLOCKS, 256, 0, stream>>>(row_start, bsum, cursor);
    scatter_kernel<<<(ETOT + 255) / 256, 256, 0, stream>>>(ei, cursor, csr_src);

    // --- layer 1 ---
    mfma_gemm_f32A<<<dim3(MB, 2), 256, 0, stream>>>(x, W1t, hbf, (float*)as_, (float*)ad_,
                                                    a_src1, a_dst1, 128);
    gather_kernel<<<NODE_WAVES, 256, 0, stream>>>((const uint2*)hbf, row_start, csr_src,
                                                  as_, ad_, (const float4*)b1, (uint2*)obf,
                                                  (const float4*)Wf, bfv, (float2*)outp, 0);

    // --- layer 2 (gather fused with post_mp) ---
    mfma_gemm_bf16A<<<dim3(MB, 2), 256, 0, stream>>>(obf, W2t, hbf, (float*)as_, (float*)ad_,
                                                     a_src2, a_dst2, 256);
    gather_kernel<<<NODE_WAVES, 256, 0, stream>>>((const uint2*)hbf, row_start, csr_src,
                                                  as_, ad_, (const float4*)b2, (uint2*)obf,
                                                  (const float4*)Wf, bfv, (float2*)outp, 1);
}